// Round 4
// baseline (258.592 us; speedup 1.0000x reference)
//
#include <hip/hip_runtime.h>

// IF (integrate-and-fire) SNN forward scan.
// x: [T*B, C, H, W] fp32 viewed as [T=8, slice=4,194,304 floats]; out same shape.
// Per element n: mem=0.5*thr; for t: mem+=x[t][n]; sp=(mem>=thr)?thr:0; mem-=sp.
//
// R1: one float4/thread, one-shot grid      -> 90 us, eff 3.0 TB/s
// R2: ILP=2 + nt stores, one-shot           -> 83 us (FETCH 64 MiB: half the
//     input is LLC-resident from the harness restore)
// R3: persistent grid-stride (1024 blocks) + nt loads+stores -> <80 us
//     (kernel left the top-5). Structure win, but nt LOADS likely forfeited
//     the LLC-warm input hits (bypass/no-allocate).
// R4: same structure, NORMAL loads (keep LLC hits) + nt stores (output is
//     single-touch; don't sweep the LLC). One-variable experiment vs R3.

typedef float f4 __attribute__((ext_vector_type(4)));

constexpr int T_STEPS = 8;
constexpr int BLOCK   = 256;
constexpr int GRID    = 1024;   // 4 blocks/CU resident, 4 iters/thread

__global__ __launch_bounds__(BLOCK) void if_fwd_kernel(
    const f4* __restrict__ x,
    const float* __restrict__ thresh,
    f4* __restrict__ out,
    int stride4)   // float4s per timestep slice
{
    const int tid      = blockIdx.x * BLOCK + threadIdx.x;
    const int nthreads = GRID * BLOCK;
    const float thr    = thresh[0];      // wave-uniform -> scalar load
    const float h      = 0.5f * thr;

    for (int i = tid; i < stride4; i += nthreads) {
        // 8 independent 16B loads in flight; normal (caching) loads so the
        // restore-warm half of the input is served by the 256 MiB LLC.
        f4 xt[T_STEPS];
#pragma unroll
        for (int t = 0; t < T_STEPS; ++t) {
            xt[t] = x[(size_t)t * stride4 + i];
        }

        f4 m = {h, h, h, h};
#pragma unroll
        for (int t = 0; t < T_STEPS; ++t) {
            m += xt[t];
            f4 s;
#pragma unroll
            for (int k = 0; k < 4; ++k) {
                s[k] = (m[k] >= thr) ? thr : 0.0f;
            }
            m -= s;
            // Output is single-touch: nt store, don't displace input in LLC.
            __builtin_nontemporal_store(s, out + (size_t)t * stride4 + i);
        }
    }
}

extern "C" void kernel_launch(void* const* d_in, const int* in_sizes, int n_in,
                              void* d_out, int out_size, void* d_ws, size_t ws_size,
                              hipStream_t stream) {
    const float* x      = (const float*)d_in[0];   // [T*B, C, H, W] fp32
    const float* thresh = (const float*)d_in[1];   // scalar threshold (1 elem)
    float* out          = (float*)d_out;

    const int total   = in_sizes[0];       // 33,554,432
    const int stride  = total / T_STEPS;   // 4,194,304 elems per slice
    const int stride4 = stride / 4;        // 1,048,576 float4s per slice

    if_fwd_kernel<<<dim3(GRID), dim3(BLOCK), 0, stream>>>(
        (const f4*)x, thresh, (f4*)out, stride4);
}

// Round 5
// 235.587 us; speedup vs baseline: 1.0977x; 1.0977x over previous
//
#include <hip/hip_runtime.h>

// IF (integrate-and-fire) SNN forward scan.
// x: [T*B, C, H, W] fp32 viewed as [T=8, slice=4,194,304 floats]; out same shape.
// Per element n: mem=0.5*thr; for t: mem+=x[t][n]; sp=(mem>=thr)?thr:0; mem-=sp.
//
// R1: one-shot float4                     -> 90 us
// R2: one-shot ILP=2 + nt stores          -> 83 us
// R3: persistent + nt loads + nt stores   -> <79.7 us (best; left rocprof top-5)
// R4: R3 but normal loads                 -> ~100 us, FETCH identical 64 MiB.
//     nt-load win is NOT traffic volume. LLC serves warm half either way.
// R5: software-pipelined prefetch: issue next tile's loads BEFORE this tile's
//     stores. vmcnt is a single in-order FIFO shared by loads+stores, so with
//     the naive order (L..L, S..S per iter) every iteration's load-wait is
//     fenced behind the previous iteration's store acks. Making next-loads
//     OLDER than current-stores in issue order decouples them.

typedef float f4 __attribute__((ext_vector_type(4)));

constexpr int T_STEPS = 8;
constexpr int BLOCK   = 256;
constexpr int GRID    = 512;    // 131072 threads -> exactly 8 iters/thread

__global__ __launch_bounds__(BLOCK) void if_fwd_kernel(
    const f4* __restrict__ x,
    const float* __restrict__ thresh,
    f4* __restrict__ out,
    int stride4)   // float4s per timestep slice (1,048,576)
{
    const int nthreads = GRID * BLOCK;
    const int tid      = blockIdx.x * BLOCK + threadIdx.x;
    const float thr    = thresh[0];      // wave-uniform -> scalar load
    const float h      = 0.5f * thr;
    const int iters    = stride4 / nthreads;   // 8 (exact division)

    int i = tid;

    // Prologue: load tile 0.
    f4 cur[T_STEPS];
#pragma unroll
    for (int t = 0; t < T_STEPS; ++t) {
        cur[t] = __builtin_nontemporal_load(x + (size_t)t * stride4 + i);
    }

    // Steady state: prefetch tile n+1 BEFORE storing tile n, so the next
    // load-wait never sits behind this iteration's store acks in vmcnt.
    for (int n = 0; n < iters - 1; ++n) {
        const int inext = i + nthreads;
        f4 nxt[T_STEPS];
#pragma unroll
        for (int t = 0; t < T_STEPS; ++t) {
            nxt[t] = __builtin_nontemporal_load(x + (size_t)t * stride4 + inext);
        }

        f4 m = {h, h, h, h};
#pragma unroll
        for (int t = 0; t < T_STEPS; ++t) {
            m += cur[t];
            f4 s;
#pragma unroll
            for (int k = 0; k < 4; ++k) {
                s[k] = (m[k] >= thr) ? thr : 0.0f;
            }
            m -= s;
            __builtin_nontemporal_store(s, out + (size_t)t * stride4 + i);
        }

#pragma unroll
        for (int t = 0; t < T_STEPS; ++t) {
            cur[t] = nxt[t];
        }
        i = inext;
    }

    // Epilogue: last tile.
    {
        f4 m = {h, h, h, h};
#pragma unroll
        for (int t = 0; t < T_STEPS; ++t) {
            m += cur[t];
            f4 s;
#pragma unroll
            for (int k = 0; k < 4; ++k) {
                s[k] = (m[k] >= thr) ? thr : 0.0f;
            }
            m -= s;
            __builtin_nontemporal_store(s, out + (size_t)t * stride4 + i);
        }
    }
}

extern "C" void kernel_launch(void* const* d_in, const int* in_sizes, int n_in,
                              void* d_out, int out_size, void* d_ws, size_t ws_size,
                              hipStream_t stream) {
    const float* x      = (const float*)d_in[0];   // [T*B, C, H, W] fp32
    const float* thresh = (const float*)d_in[1];   // scalar threshold (1 elem)
    float* out          = (float*)d_out;

    const int total   = in_sizes[0];       // 33,554,432
    const int stride  = total / T_STEPS;   // 4,194,304 elems per slice
    const int stride4 = stride / 4;        // 1,048,576 float4s per slice

    if_fwd_kernel<<<dim3(GRID), dim3(BLOCK), 0, stream>>>(
        (const f4*)x, thresh, (f4*)out, stride4);
}